// Round 2
// baseline (15552.228 us; speedup 1.0000x reference)
//
#include <hip/hip_runtime.h>
#include <cstdint>
#include <cmath>

#define V 32000
#define E 512
#define H 1024
#define B 128
#define S 64
#define NCHUNK 8
#define CHUNK 4000       // V / NCHUNK
#define BS (B*S)

// ---------------- threefry2x32 (JAX-exact, 20 rounds) ----------------
#define TFR(x0, x1, r) { x0 += x1; x1 = ((x1) << (r)) | ((x1) >> (32 - (r))); x1 ^= x0; }

__host__ __device__ inline void tf2x32(uint32_t k0, uint32_t k1, uint32_t &x0, uint32_t &x1) {
  uint32_t ks2 = k0 ^ k1 ^ 0x1BD11BDAu;
  x0 += k0; x1 += k1;
  TFR(x0,x1,13) TFR(x0,x1,15) TFR(x0,x1,26) TFR(x0,x1,6)
  x0 += k1;  x1 += ks2 + 1u;
  TFR(x0,x1,17) TFR(x0,x1,29) TFR(x0,x1,16) TFR(x0,x1,24)
  x0 += ks2; x1 += k0 + 2u;
  TFR(x0,x1,13) TFR(x0,x1,15) TFR(x0,x1,26) TFR(x0,x1,6)
  x0 += k0;  x1 += k1 + 3u;
  TFR(x0,x1,17) TFR(x0,x1,29) TFR(x0,x1,16) TFR(x0,x1,24)
  x0 += k1;  x1 += ks2 + 4u;
  TFR(x0,x1,13) TFR(x0,x1,15) TFR(x0,x1,26) TFR(x0,x1,6)
  x0 += ks2; x1 += k0 + 5u;
}

// partitionable threefry 32-bit random bits: xor of both output words of enc(hi=0, lo=i)
__device__ __forceinline__ uint32_t tf_bits32(uint32_t ka, uint32_t kb, uint32_t idx) {
  uint32_t x0 = 0u, x1 = idx;
  tf2x32(ka, kb, x0, x1);
  return x0 ^ x1;
}

__device__ __forceinline__ float bits_to_unif(uint32_t b) {
  // JAX: bitcast((bits>>9) | 0x3f800000) - 1.0
  return __uint_as_float((b >> 9) | 0x3f800000u) - 1.0f;
}

__device__ __forceinline__ float sigmoidf_(float x) { return 1.0f / (1.0f + expf(-x)); }

// ---------------- generic f32 GEMM tile: C[m,n] = sum_k A[m,k]*W[n,k] + bias[n] ----------------
template<int BM, int BN, int BK, int TM, int TN>
__device__ void gemm_tile(const float* __restrict__ A, const float* __restrict__ Wt,
                          const float* __restrict__ bias, float* __restrict__ C,
                          int N, int K, int mblk, int nblk)
{
  constexpr int WP = BN + 4;
  __shared__ __align__(16) float As[BK][BM];
  __shared__ __align__(16) float Ws[BK][WP];
  const int tid = threadIdx.x;
  constexpr int TX = BN / TN;    // threads along cols
  constexpr int TY = BM / TM;    // threads along rows (TX*TY == 256)
  static_assert(TX * TY == 256, "bad tiling");
  const int tx = tid % TX, ty = tid / TX;
  const int n0 = tx * TN, m0 = ty * TM;

  float acc[TM][TN];
#pragma unroll
  for (int i = 0; i < TM; ++i)
#pragma unroll
    for (int j = 0; j < TN; ++j) acc[i][j] = 0.0f;

  constexpr int NA = (BM * BK / 4) / 256;   // float4s per thread for A
  constexpr int NW = (BN * BK / 4) / 256;   // float4s per thread for W
  static_assert(NA >= 1 && NW >= 1, "tile too small");

  for (int k0 = 0; k0 < K; k0 += BK) {
    __syncthreads();
#pragma unroll
    for (int q = 0; q < NA; ++q) {
      int idx = q * 256 + tid;
      int m = idx / (BK / 4), c = idx % (BK / 4);
      float4 v = *(const float4*)&A[(size_t)(mblk + m) * K + k0 + 4 * c];
      As[4*c+0][m] = v.x; As[4*c+1][m] = v.y; As[4*c+2][m] = v.z; As[4*c+3][m] = v.w;
    }
#pragma unroll
    for (int q = 0; q < NW; ++q) {
      int idx = q * 256 + tid;
      int n = idx / (BK / 4), c = idx % (BK / 4);
      float4 v = *(const float4*)&Wt[(size_t)(nblk + n) * K + k0 + 4 * c];
      Ws[4*c+0][n] = v.x; Ws[4*c+1][n] = v.y; Ws[4*c+2][n] = v.z; Ws[4*c+3][n] = v.w;
    }
    __syncthreads();
#pragma unroll
    for (int k = 0; k < BK; ++k) {
      float a[TM], w[TN];
#pragma unroll
      for (int i = 0; i < TM; ++i) a[i] = As[k][m0 + i];
#pragma unroll
      for (int j = 0; j < TN; ++j) w[j] = Ws[k][n0 + j];
#pragma unroll
      for (int i = 0; i < TM; ++i)
#pragma unroll
        for (int j = 0; j < TN; ++j) acc[i][j] += a[i] * w[j];
    }
  }
#pragma unroll
  for (int i = 0; i < TM; ++i) {
#pragma unroll
    for (int j = 0; j < TN; ++j) {
      C[(size_t)(mblk + m0 + i) * N + nblk + n0 + j] = acc[i][j] + bias[nblk + n0 + j];
    }
  }
}

// dist GEMM: logits[128,32000] = h[128,1024] @ w_dist[32000,1024]^T + b_dist
__global__ __launch_bounds__(256) void gemm_dist_k(const float* __restrict__ h,
    const float* __restrict__ w_dist, const float* __restrict__ b_dist,
    float* __restrict__ logits)
{
  gemm_tile<128, 64, 16, 8, 4>(h, w_dist, b_dist, logits, V, H, 0, blockIdx.x * 64);
}

// GRU gemms: gx = x @ w_ih^T + b_ih (K=512), gh = h @ w_hh^T + b_hh (K=1024)
__global__ __launch_bounds__(256) void gemm_gru_k(const float* __restrict__ x,
    const float* __restrict__ h, const float* __restrict__ w_ih, const float* __restrict__ w_hh,
    const float* __restrict__ b_ih, const float* __restrict__ b_hh,
    float* __restrict__ gx, float* __restrict__ gh)
{
  int b = blockIdx.x;
  if (b < 96) {
    int rb = b & 1, cb = b >> 1;
    gemm_tile<64, 64, 16, 4, 4>(x, w_ih, b_ih, gx, 3 * H, E, rb * 64, cb * 64);
  } else {
    b -= 96;
    int rb = b & 1, cb = b >> 1;
    gemm_tile<64, 64, 16, 4, 4>(h, w_hh, b_hh, gh, 3 * H, H, rb * 64, cb * 64);
  }
}

// GRU gates, h updated in place
__global__ __launch_bounds__(256) void gru_gates_k(const float* __restrict__ gx,
    const float* __restrict__ gh, float* __restrict__ h)
{
  int idx = blockIdx.x * 256 + threadIdx.x;   // B*H = 131072
  int b = idx >> 10, j = idx & 1023;
  const float* gxb = gx + (size_t)b * 3 * H;
  const float* ghb = gh + (size_t)b * 3 * H;
  float r = sigmoidf_(gxb[j] + ghb[j]);
  float z = sigmoidf_(gxb[H + j] + ghb[H + j]);
  float n = tanhf(gxb[2 * H + j] + r * ghb[2 * H + j]);
  h[idx] = (1.0f - z) * n + z * h[idx];
}

// init: h = 0, x = broadcast emb[0]
__global__ __launch_bounds__(256) void init_k(const float* __restrict__ emb,
    float* __restrict__ h, float* __restrict__ x)
{
  int i = blockIdx.x * 256 + threadIdx.x;   // grid covers B*H
  if (i < B * H) h[i] = 0.0f;
  if (i < B * E) x[i] = emb[i & (E - 1)];
}

// pass 1: per (row, v-chunk) online softmax partials (m, s)
__global__ __launch_bounds__(256) void rowstat_partial_k(const float* __restrict__ logits,
    float* __restrict__ pm, float* __restrict__ ps)
{
  const int b = blockIdx.x & 127, chunk = blockIdx.x >> 7;
  const int tid = threadIdx.x;
  const int vbeg = chunk * CHUNK, vend = vbeg + CHUNK;
  float m0 = -INFINITY, s0 = 0.0f;
  for (int v = vbeg + tid; v < vend; v += 256) {
    float a = logits[(size_t)b * V + v];
    if (a > m0) { s0 = s0 * expf(m0 - a) + 1.0f; m0 = a; } else { s0 += expf(a - m0); }
  }
  __shared__ float shm[256], shs[256];
  shm[tid] = m0; shs[tid] = s0;
  __syncthreads();
  for (int off = 128; off > 0; off >>= 1) {
    if (tid < off) {
      float ma = shm[tid], sa = shs[tid];
      float mb = shm[tid + off], sb = shs[tid + off];
      float M = fmaxf(ma, mb);
      shm[tid] = M;
      shs[tid] = sa * expf(ma - M) + sb * expf(mb - M);
    }
    __syncthreads();
  }
  if (tid == 0) {
    pm[b * NCHUNK + chunk] = shm[0]; ps[b * NCHUNK + chunk] = shs[0];
  }
}

// pass 2: combine stats, compute gumbel argmax partials per (row, chunk)
__global__ __launch_bounds__(256) void argmax_partial_k(const float* __restrict__ logits,
    const float* __restrict__ pm, const float* __restrict__ ps,
    float* __restrict__ rowm, float* __restrict__ rowz,
    float* __restrict__ pbest, int* __restrict__ pidx,
    uint32_t k1a, uint32_t k1b, uint32_t k2a, uint32_t k2b)
{
  const int b = blockIdx.x & 127, chunk = blockIdx.x >> 7;
  const int tid = threadIdx.x;
  // combine the 8 chunk partials (redundant per thread, cheap + deterministic)
  float m0 = -INFINITY, s0 = 0.0f;
#pragma unroll
  for (int c = 0; c < NCHUNK; ++c) {
    float ma = pm[b * NCHUNK + c], sa = ps[b * NCHUNK + c];
    float M = fmaxf(m0, ma); s0 = s0 * expf(m0 - M) + sa * expf(ma - M); m0 = M;
  }
  float z0 = logf(s0);
  if (chunk == 0 && tid == 0) { rowm[b] = m0; rowz[b] = z0; }
  // epsilon-draw decision: bits = xorfold(threefry(k1, [0, b]))
  bool draw0 = bits_to_unif(tf_bits32(k1a, k1b, (uint32_t)b)) <= 0.05f;
  const float LOGU = -logf((float)V);
  float best0 = -INFINITY;
  int i0 = 2147483647;
  const int vbeg = chunk * CHUNK, vend = vbeg + CHUNK;
  for (int v = vbeg + tid; v < vend; v += 256) {
    uint32_t bits = tf_bits32(k2a, k2b, (uint32_t)(b * V + v));
    float g0 = -logf(-logf(bits_to_unif(bits)));
    float dn0 = draw0 ? LOGU : ((logits[(size_t)b * V + v] - m0) - z0);
    float v0 = dn0 + g0;
    if (v0 > best0) { best0 = v0; i0 = v; }   // ascending v => first-max kept
  }
  __shared__ float sv[256];
  __shared__ int   si[256];
  sv[tid] = best0; si[tid] = i0;
  __syncthreads();
  for (int off = 128; off > 0; off >>= 1) {
    if (tid < off) {
      float va = sv[tid], vb = sv[tid + off];
      int ia = si[tid], ib = si[tid + off];
      if (vb > va || (vb == va && ib < ia)) { sv[tid] = vb; si[tid] = ib; }
    }
    __syncthreads();
  }
  if (tid == 0) {
    pbest[b * NCHUNK + chunk] = sv[0]; pidx[b * NCHUNK + chunk] = si[0];
  }
}

// final: combine chunk partials, emit samp/corr/lp, gather next x = emb[sampled]
__global__ __launch_bounds__(256) void sample_final_k(const float* __restrict__ logits,
    const float* __restrict__ rowm, const float* __restrict__ rowz,
    const float* __restrict__ pbest, const int* __restrict__ pidx,
    const float* __restrict__ emb, float* __restrict__ x,
    float* __restrict__ out, int t, uint32_t k1a, uint32_t k1b)
{
  __shared__ int sh_idx[B];
  const int tid = threadIdx.x;
  if (tid < B) {
    const int b = tid;
    float best = pbest[b * NCHUNK]; int idx = pidx[b * NCHUNK];
#pragma unroll
    for (int c = 1; c < NCHUNK; ++c) {
      float v = pbest[b * NCHUNK + c];
      if (v > best) { best = v; idx = pidx[b * NCHUNK + c]; }  // chunk order = v order
    }
    float lp = (logits[(size_t)b * V + idx] - rowm[b]) - rowz[b];
    float u = bits_to_unif(tf_bits32(k1a, k1b, (uint32_t)b));
    bool draw = u <= 0.05f;
    float corr = 1.0f;   // non-drawn rows: onp == offp exactly
    if (draw) {
      const float LOGU = -logf((float)V);
      float onp = fminf(fmaxf(expf(lp), 1e-8f), 1.0f);
      float offp = fminf(fmaxf(expf(LOGU), 1e-8f), 1.0f);
      corr = onp / offp;
    }
    out[b * S + t] = (float)idx;
    out[BS + b * S + t] = corr;
    out[2 * BS + b * S + t] = lp;
    sh_idx[b] = idx;
  }
  __syncthreads();
  for (int i = tid; i < B * E; i += 256) {
    x[i] = emb[(size_t)sh_idx[i >> 9] * E + (i & (E - 1))];
  }
}

// probs[t, v] = mean_b exp(dist[b, v])
__global__ __launch_bounds__(256) void probs_k(const float* __restrict__ logits,
    const float* __restrict__ rowm, const float* __restrict__ rowz,
    float* __restrict__ out, int t)
{
  __shared__ float sm[B], sz[B];
  const int tid = threadIdx.x;
  if (tid < B) { sm[tid] = rowm[tid]; sz[tid] = rowz[tid]; }
  __syncthreads();
  int v = blockIdx.x * 256 + tid;   // 125 blocks * 256 = 32000
  float acc = 0.0f;
  for (int b = 0; b < B; ++b) acc += expf((logits[(size_t)b * V + v] - sm[b]) - sz[b]);
  out[3 * BS + (size_t)t * V + v] = acc * (1.0f / 128.0f);
}

extern "C" void kernel_launch(void* const* d_in, const int* in_sizes, int n_in,
                              void* d_out, int out_size, void* d_ws, size_t ws_size,
                              hipStream_t stream) {
  (void)in_sizes; (void)n_in; (void)out_size; (void)ws_size;
  const float* emb    = (const float*)d_in[0];
  const float* w_ih   = (const float*)d_in[1];
  const float* w_hh   = (const float*)d_in[2];
  const float* b_ih   = (const float*)d_in[3];
  const float* b_hh   = (const float*)d_in[4];
  const float* w_dist = (const float*)d_in[5];
  const float* b_dist = (const float*)d_in[6];
  float* out = (float*)d_out;

  float* ws = (float*)d_ws;
  float* h      = ws;                  // B*H
  float* x      = h + B * H;           // B*E
  float* gx     = x + B * E;           // B*3H
  float* gh     = gx + B * 3 * H;      // B*3H
  float* logits = gh + B * 3 * H;      // B*V
  float* pm     = logits + (size_t)B * V;  // B*NCHUNK
  float* ps     = pm + B * NCHUNK;
  float* pbest  = ps + B * NCHUNK;
  int*   pidx   = (int*)(pbest + B * NCHUNK);
  float* rowm   = (float*)(pidx + B * NCHUNK);
  float* rowz   = rowm + B;

  init_k<<<512, 256, 0, stream>>>(emb, h, x);

  const uint32_t base0 = 0u, base1 = 42u;   // jax.random.key(42)
  for (int t = 0; t < S; ++t) {
    // host-side key derivation (partitionable threefry):
    //   k_t = fold_in(base, t) = threefry(base, [0, t])        (both output words)
    //   split(k_t): k1 = threefry(k_t, [0, 0]), k2 = threefry(k_t, [0, 1])
    uint32_t f0 = 0u, f1 = (uint32_t)t;
    tf2x32(base0, base1, f0, f1);           // k_t = (f0, f1)
    uint32_t k1a = 0u, k1b = 0u; tf2x32(f0, f1, k1a, k1b);   // k1 = enc(0,0)
    uint32_t k2a = 0u, k2b = 1u; tf2x32(f0, f1, k2a, k2b);   // k2 = enc(0,1)

    gemm_gru_k<<<192, 256, 0, stream>>>(x, h, w_ih, w_hh, b_ih, b_hh, gx, gh);
    gru_gates_k<<<512, 256, 0, stream>>>(gx, gh, h);
    gemm_dist_k<<<500, 256, 0, stream>>>(h, w_dist, b_dist, logits);
    rowstat_partial_k<<<1024, 256, 0, stream>>>(logits, pm, ps);
    argmax_partial_k<<<1024, 256, 0, stream>>>(logits, pm, ps, rowm, rowz, pbest, pidx,
                                               k1a, k1b, k2a, k2b);
    sample_final_k<<<1, 256, 0, stream>>>(logits, rowm, rowz, pbest, pidx, emb, x,
                                          out, t, k1a, k1b);
    probs_k<<<125, 256, 0, stream>>>(logits, rowm, rowz, out, t);
  }
}

// Round 3
// 9185.134 us; speedup vs baseline: 1.6932x; 1.6932x over previous
//
#include <hip/hip_runtime.h>
#include <cstdint>
#include <cmath>

#define V 32000
#define E 512
#define H 1024
#define B 128
#define S 64
#define NCHUNK 8
#define CHUNK 4000       // V / NCHUNK
#define BS (B*S)

typedef __attribute__((ext_vector_type(8))) short short8;
typedef __attribute__((ext_vector_type(4))) float f32x4;

// ---------------- threefry2x32 (JAX-exact, 20 rounds) ----------------
#define TFR(x0, x1, r) { x0 += x1; x1 = ((x1) << (r)) | ((x1) >> (32 - (r))); x1 ^= x0; }

__host__ __device__ inline void tf2x32(uint32_t k0, uint32_t k1, uint32_t &x0, uint32_t &x1) {
  uint32_t ks2 = k0 ^ k1 ^ 0x1BD11BDAu;
  x0 += k0; x1 += k1;
  TFR(x0,x1,13) TFR(x0,x1,15) TFR(x0,x1,26) TFR(x0,x1,6)
  x0 += k1;  x1 += ks2 + 1u;
  TFR(x0,x1,17) TFR(x0,x1,29) TFR(x0,x1,16) TFR(x0,x1,24)
  x0 += ks2; x1 += k0 + 2u;
  TFR(x0,x1,13) TFR(x0,x1,15) TFR(x0,x1,26) TFR(x0,x1,6)
  x0 += k0;  x1 += k1 + 3u;
  TFR(x0,x1,17) TFR(x0,x1,29) TFR(x0,x1,16) TFR(x0,x1,24)
  x0 += k1;  x1 += ks2 + 4u;
  TFR(x0,x1,13) TFR(x0,x1,15) TFR(x0,x1,26) TFR(x0,x1,6)
  x0 += ks2; x1 += k0 + 5u;
}

// partitionable threefry 32-bit random bits: xor of both output words of enc(hi=0, lo=i)
__device__ __forceinline__ uint32_t tf_bits32(uint32_t ka, uint32_t kb, uint32_t idx) {
  uint32_t x0 = 0u, x1 = idx;
  tf2x32(ka, kb, x0, x1);
  return x0 ^ x1;
}

__device__ __forceinline__ float bits_to_unif(uint32_t b) {
  return __uint_as_float((b >> 9) | 0x3f800000u) - 1.0f;
}

__device__ __forceinline__ float sigmoidf_(float x) { return 1.0f / (1.0f + expf(-x)); }

// bf16 round-to-nearest-even helpers
__device__ __forceinline__ ushort f2bf(float f) {
  uint32_t u = __float_as_uint(f);
  uint32_t r = u + 0x7FFFu + ((u >> 16) & 1u);
  return (ushort)(r >> 16);
}
__device__ __forceinline__ float bf2f(ushort h) { return __uint_as_float(((uint32_t)h) << 16); }

// ---------------- f32 GEMM tile (GRU + fallback dist) ----------------
template<int BM, int BN, int BK, int TM, int TN>
__device__ void gemm_tile(const float* __restrict__ A, const float* __restrict__ Wt,
                          const float* __restrict__ bias, float* __restrict__ C,
                          int N, int K, int mblk, int nblk)
{
  constexpr int WP = BN + 4;
  __shared__ __align__(16) float As[BK][BM];
  __shared__ __align__(16) float Ws[BK][WP];
  const int tid = threadIdx.x;
  constexpr int TX = BN / TN;
  constexpr int TY = BM / TM;
  static_assert(TX * TY == 256, "bad tiling");
  const int tx = tid % TX, ty = tid / TX;
  const int n0 = tx * TN, m0 = ty * TM;

  float acc[TM][TN];
#pragma unroll
  for (int i = 0; i < TM; ++i)
#pragma unroll
    for (int j = 0; j < TN; ++j) acc[i][j] = 0.0f;

  constexpr int NA = (BM * BK / 4) / 256;
  constexpr int NW = (BN * BK / 4) / 256;
  static_assert(NA >= 1 && NW >= 1, "tile too small");

  for (int k0 = 0; k0 < K; k0 += BK) {
    __syncthreads();
#pragma unroll
    for (int q = 0; q < NA; ++q) {
      int idx = q * 256 + tid;
      int m = idx / (BK / 4), c = idx % (BK / 4);
      float4 v = *(const float4*)&A[(size_t)(mblk + m) * K + k0 + 4 * c];
      As[4*c+0][m] = v.x; As[4*c+1][m] = v.y; As[4*c+2][m] = v.z; As[4*c+3][m] = v.w;
    }
#pragma unroll
    for (int q = 0; q < NW; ++q) {
      int idx = q * 256 + tid;
      int n = idx / (BK / 4), c = idx % (BK / 4);
      float4 v = *(const float4*)&Wt[(size_t)(nblk + n) * K + k0 + 4 * c];
      Ws[4*c+0][n] = v.x; Ws[4*c+1][n] = v.y; Ws[4*c+2][n] = v.z; Ws[4*c+3][n] = v.w;
    }
    __syncthreads();
#pragma unroll
    for (int k = 0; k < BK; ++k) {
      float a[TM], w[TN];
#pragma unroll
      for (int i = 0; i < TM; ++i) a[i] = As[k][m0 + i];
#pragma unroll
      for (int j = 0; j < TN; ++j) w[j] = Ws[k][n0 + j];
#pragma unroll
      for (int i = 0; i < TM; ++i)
#pragma unroll
        for (int j = 0; j < TN; ++j) acc[i][j] += a[i] * w[j];
    }
  }
#pragma unroll
  for (int i = 0; i < TM; ++i)
#pragma unroll
    for (int j = 0; j < TN; ++j)
      C[(size_t)(mblk + m0 + i) * N + nblk + n0 + j] = acc[i][j] + bias[nblk + n0 + j];
}

// fallback dist GEMM (f32)
__global__ __launch_bounds__(256) void gemm_dist_k(const float* __restrict__ h,
    const float* __restrict__ w_dist, const float* __restrict__ b_dist,
    float* __restrict__ logits)
{
  gemm_tile<128, 64, 16, 8, 4>(h, w_dist, b_dist, logits, V, H, 0, blockIdx.x * 64);
}

// GRU gemms: gx = x @ w_ih^T + b_ih (K=512), gh = h @ w_hh^T + b_hh (K=1024)
__global__ __launch_bounds__(256) void gemm_gru_k(const float* __restrict__ x,
    const float* __restrict__ h, const float* __restrict__ w_ih, const float* __restrict__ w_hh,
    const float* __restrict__ b_ih, const float* __restrict__ b_hh,
    float* __restrict__ gx, float* __restrict__ gh)
{
  int b = blockIdx.x;
  if (b < 96) {
    int rb = b & 1, cb = b >> 1;
    gemm_tile<64, 64, 16, 4, 4>(x, w_ih, b_ih, gx, 3 * H, E, rb * 64, cb * 64);
  } else {
    b -= 96;
    int rb = b & 1, cb = b >> 1;
    gemm_tile<64, 64, 16, 4, 4>(h, w_hh, b_hh, gh, 3 * H, H, rb * 64, cb * 64);
  }
}

// split w_dist f32 -> bf16 hi/lo (once per call)
__global__ __launch_bounds__(256) void wsplit_k(const float* __restrict__ w,
    ushort* __restrict__ whi, ushort* __restrict__ wlo)
{
  size_t i = ((size_t)blockIdx.x * 256 + threadIdx.x) * 4;   // 32000 blocks
  float4 v = *(const float4*)&w[i];
  ushort h0 = f2bf(v.x), h1 = f2bf(v.y), h2 = f2bf(v.z), h3 = f2bf(v.w);
  ushort l0 = f2bf(v.x - bf2f(h0)), l1 = f2bf(v.y - bf2f(h1));
  ushort l2 = f2bf(v.z - bf2f(h2)), l3 = f2bf(v.w - bf2f(h3));
  ushort4 hv = {h0, h1, h2, h3}, lv = {l0, l1, l2, l3};
  *(ushort4*)&whi[i] = hv;
  *(ushort4*)&wlo[i] = lv;
}

// GRU gates, h updated in place; also emits bf16 hi/lo split of h
__global__ __launch_bounds__(256) void gru_gates_k(const float* __restrict__ gx,
    const float* __restrict__ gh, float* __restrict__ h,
    ushort* __restrict__ hhi, ushort* __restrict__ hlo)
{
  int idx = blockIdx.x * 256 + threadIdx.x;   // B*H = 131072
  int b = idx >> 10, j = idx & 1023;
  const float* gxb = gx + (size_t)b * 3 * H;
  const float* ghb = gh + (size_t)b * 3 * H;
  float r = sigmoidf_(gxb[j] + ghb[j]);
  float z = sigmoidf_(gxb[H + j] + ghb[H + j]);
  float n = tanhf(gxb[2 * H + j] + r * ghb[2 * H + j]);
  float hn = (1.0f - z) * n + z * h[idx];
  h[idx] = hn;
  ushort hi = f2bf(hn);
  hhi[idx] = hi;
  hlo[idx] = f2bf(hn - bf2f(hi));
}

// ---------------- MFMA bf16x3 dist GEMM ----------------
// logits[128,32000] = h[128,1024] @ w_dist^T + b_dist, via Ah*Wh + Al*Wh + Ah*Wl
// 250 blocks x 512 threads (8 waves). Block tile 128(M) x 128(N). BK=32.
// LDS row stride 40 ushorts (80 B): 16B-aligned, bank-uniform (20 words * m mod 32).
#define PS 40
__global__ __launch_bounds__(512) void gemm_dist_mfma(const ushort* __restrict__ hhi,
    const ushort* __restrict__ hlo, const ushort* __restrict__ whi,
    const ushort* __restrict__ wlo, const float* __restrict__ b_dist,
    float* __restrict__ logits)
{
  __shared__ ushort Ah[128 * PS], Al[128 * PS], Wh[128 * PS], Wl[128 * PS];
  const int tid = threadIdx.x;
  const int wave = tid >> 6, lane = tid & 63;
  const int wm = (wave & 3) * 32;        // wave m-offset: 0/32/64/96
  const int wn = (wave >> 2) * 64;       // wave n-offset: 0/64
  const int nblk = blockIdx.x * 128;
  const int l15 = lane & 15;
  const int q8 = (lane >> 4) * 8;

  f32x4 acc[2][4] = {};

  // staging map: thread -> (row r = tid>>2, col c = (tid&3)*8), one 16B vec per array
  const int sr = tid >> 2, sc = (tid & 3) * 8;

  for (int k0 = 0; k0 < 1024; k0 += 32) {
    __syncthreads();
    uint4 va = *(const uint4*)&hhi[(size_t)sr * 1024 + k0 + sc];
    uint4 vb = *(const uint4*)&hlo[(size_t)sr * 1024 + k0 + sc];
    uint4 vc = *(const uint4*)&whi[(size_t)(nblk + sr) * 1024 + k0 + sc];
    uint4 vd = *(const uint4*)&wlo[(size_t)(nblk + sr) * 1024 + k0 + sc];
    *(uint4*)&Ah[sr * PS + sc] = va;
    *(uint4*)&Al[sr * PS + sc] = vb;
    *(uint4*)&Wh[sr * PS + sc] = vc;
    *(uint4*)&Wl[sr * PS + sc] = vd;
    __syncthreads();

    short8 ah[2], al[2], wh[4], wl[4];
#pragma unroll
    for (int mt = 0; mt < 2; ++mt) {
      int row = wm + mt * 16 + l15;
      ah[mt] = *(const short8*)&Ah[row * PS + q8];
      al[mt] = *(const short8*)&Al[row * PS + q8];
    }
#pragma unroll
    for (int nt = 0; nt < 4; ++nt) {
      int row = wn + nt * 16 + l15;
      wh[nt] = *(const short8*)&Wh[row * PS + q8];
      wl[nt] = *(const short8*)&Wl[row * PS + q8];
    }
#pragma unroll
    for (int mt = 0; mt < 2; ++mt)
#pragma unroll
      for (int nt = 0; nt < 4; ++nt) {
        acc[mt][nt] = __builtin_amdgcn_mfma_f32_16x16x32_bf16(ah[mt], wh[nt], acc[mt][nt], 0, 0, 0);
        acc[mt][nt] = __builtin_amdgcn_mfma_f32_16x16x32_bf16(al[mt], wh[nt], acc[mt][nt], 0, 0, 0);
        acc[mt][nt] = __builtin_amdgcn_mfma_f32_16x16x32_bf16(ah[mt], wl[nt], acc[mt][nt], 0, 0, 0);
      }
  }

  // epilogue: C row = wm + mt*16 + (lane>>4)*4 + reg, col = wn + nt*16 + (lane&15)
#pragma unroll
  for (int nt = 0; nt < 4; ++nt) {
    int col = nblk + wn + nt * 16 + l15;
    float bv = b_dist[col];
#pragma unroll
    for (int mt = 0; mt < 2; ++mt) {
      int rbase = wm + mt * 16 + (lane >> 4) * 4;
#pragma unroll
      for (int reg = 0; reg < 4; ++reg)
        logits[(size_t)(rbase + reg) * V + col] = acc[mt][nt][reg] + bv;
    }
  }
}

// init: h = 0, x = broadcast emb[0]
__global__ __launch_bounds__(256) void init_k(const float* __restrict__ emb,
    float* __restrict__ h, float* __restrict__ x)
{
  int i = blockIdx.x * 256 + threadIdx.x;
  if (i < B * H) h[i] = 0.0f;
  if (i < B * E) x[i] = emb[i & (E - 1)];
}

// fused pass: per (row, v-chunk) online softmax partials AND gumbel-argmax partials.
// key = draw ? (LOGU + g) : (logits + g)   (row-constant shift doesn't change argmax)
__global__ __launch_bounds__(256) void sample_partial_k(const float* __restrict__ logits,
    float* __restrict__ pm, float* __restrict__ ps,
    float* __restrict__ pbest, int* __restrict__ pidx,
    uint32_t k1a, uint32_t k1b, uint32_t k2a, uint32_t k2b)
{
  const int b = blockIdx.x & 127, chunk = blockIdx.x >> 7;
  const int tid = threadIdx.x;
  const bool draw = bits_to_unif(tf_bits32(k1a, k1b, (uint32_t)b)) <= 0.05f;
  const float LOGU = -logf((float)V);
  const int vbeg = chunk * CHUNK, vend = vbeg + CHUNK;
  float m0 = -INFINITY, s0 = 0.0f, best = -INFINITY;
  int bi = 2147483647;
  for (int v = vbeg + tid; v < vend; v += 256) {
    float a = logits[(size_t)b * V + v];
    if (a > m0) { s0 = s0 * expf(m0 - a) + 1.0f; m0 = a; } else { s0 += expf(a - m0); }
    uint32_t bits = tf_bits32(k2a, k2b, (uint32_t)(b * V + v));
    float g = -logf(-logf(bits_to_unif(bits)));
    float key = draw ? (LOGU + g) : (a + g);
    if (key > best) { best = key; bi = v; }
  }
  __shared__ float shm[256], shs[256], sv[256];
  __shared__ int si[256];
  shm[tid] = m0; shs[tid] = s0; sv[tid] = best; si[tid] = bi;
  __syncthreads();
  for (int off = 128; off > 0; off >>= 1) {
    if (tid < off) {
      float ma = shm[tid], sa = shs[tid];
      float mb = shm[tid + off], sb = shs[tid + off];
      float M = fmaxf(ma, mb);
      shm[tid] = M;
      shs[tid] = sa * expf(ma - M) + sb * expf(mb - M);
      float va = sv[tid], vb = sv[tid + off];
      int ia = si[tid], ib = si[tid + off];
      if (vb > va || (vb == va && ib < ia)) { sv[tid] = vb; si[tid] = ib; }
    }
    __syncthreads();
  }
  if (tid == 0) {
    pm[b * NCHUNK + chunk] = shm[0]; ps[b * NCHUNK + chunk] = shs[0];
    pbest[b * NCHUNK + chunk] = sv[0]; pidx[b * NCHUNK + chunk] = si[0];
  }
}

// final: combine chunk partials -> rowm/rowz, sampled idx, emit samp/corr/lp
__global__ __launch_bounds__(128) void sample_final_k(const float* __restrict__ logits,
    const float* __restrict__ pm, const float* __restrict__ ps,
    const float* __restrict__ pbest, const int* __restrict__ pidx,
    float* __restrict__ rowm, float* __restrict__ rowz, int* __restrict__ samp,
    float* __restrict__ out, int t, uint32_t k1a, uint32_t k1b)
{
  const int b = threadIdx.x;   // 128 threads
  float m0 = -INFINITY, s0 = 0.0f;
#pragma unroll
  for (int c = 0; c < NCHUNK; ++c) {
    float ma = pm[b * NCHUNK + c], sa = ps[b * NCHUNK + c];
    float M = fmaxf(m0, ma); s0 = s0 * expf(m0 - M) + sa * expf(ma - M); m0 = M;
  }
  float z0 = logf(s0);
  rowm[b] = m0; rowz[b] = z0;
  float best = pbest[b * NCHUNK]; int idx = pidx[b * NCHUNK];
#pragma unroll
  for (int c = 1; c < NCHUNK; ++c) {
    float v = pbest[b * NCHUNK + c];
    if (v > best) { best = v; idx = pidx[b * NCHUNK + c]; }
  }
  float lp = (logits[(size_t)b * V + idx] - m0) - z0;
  bool draw = bits_to_unif(tf_bits32(k1a, k1b, (uint32_t)b)) <= 0.05f;
  float corr = 1.0f;
  if (draw) {
    const float LOGU = -logf((float)V);
    float onp = fminf(fmaxf(expf(lp), 1e-8f), 1.0f);
    float offp = fminf(fmaxf(expf(LOGU), 1e-8f), 1.0f);
    corr = onp / offp;
  }
  out[b * S + t] = (float)idx;
  out[BS + b * S + t] = corr;
  out[2 * BS + b * S + t] = lp;
  samp[b] = idx;
}

// gather next x = emb[sampled] : one block per row
__global__ __launch_bounds__(128) void gather_x_k(const float* __restrict__ emb,
    const int* __restrict__ samp, float* __restrict__ x)
{
  const int b = blockIdx.x;
  const int row = samp[b];
  const float4 v = ((const float4*)&emb[(size_t)row * E])[threadIdx.x];
  ((float4*)&x[(size_t)b * E])[threadIdx.x] = v;
}

// probs[t, v] = mean_b exp(dist[b, v])
__global__ __launch_bounds__(256) void probs_k(const float* __restrict__ logits,
    const float* __restrict__ rowm, const float* __restrict__ rowz,
    float* __restrict__ out, int t)
{
  __shared__ float sm[B], sz[B];
  const int tid = threadIdx.x;
  if (tid < B) { sm[tid] = rowm[tid]; sz[tid] = rowz[tid]; }
  __syncthreads();
  int v = blockIdx.x * 256 + tid;
  float acc = 0.0f;
  for (int b = 0; b < B; ++b) acc += expf((logits[(size_t)b * V + v] - sm[b]) - sz[b]);
  out[3 * BS + (size_t)t * V + v] = acc * (1.0f / 128.0f);
}

extern "C" void kernel_launch(void* const* d_in, const int* in_sizes, int n_in,
                              void* d_out, int out_size, void* d_ws, size_t ws_size,
                              hipStream_t stream) {
  (void)in_sizes; (void)n_in; (void)out_size;
  const float* emb    = (const float*)d_in[0];
  const float* w_ih   = (const float*)d_in[1];
  const float* w_hh   = (const float*)d_in[2];
  const float* b_ih   = (const float*)d_in[3];
  const float* b_hh   = (const float*)d_in[4];
  const float* w_dist = (const float*)d_in[5];
  const float* b_dist = (const float*)d_in[6];
  float* out = (float*)d_out;

  float* ws = (float*)d_ws;
  float* h      = ws;                      // B*H
  float* x      = h + B * H;               // B*E
  float* gx     = x + B * E;               // B*3H
  float* gh     = gx + B * 3 * H;          // B*3H
  float* logits = gh + B * 3 * H;          // B*V
  float* pm     = logits + (size_t)B * V;  // B*NCHUNK
  float* ps     = pm + B * NCHUNK;
  float* pbest  = ps + B * NCHUNK;
  int*   pidx   = (int*)(pbest + B * NCHUNK);
  float* rowm   = (float*)(pidx + B * NCHUNK);
  float* rowz   = rowm + B;
  int*   samp   = (int*)(rowz + B);
  ushort* hhi   = (ushort*)(samp + B);                 // B*H ushorts
  ushort* hlo   = hhi + (size_t)B * H;                 // B*H ushorts
  ushort* whi   = hlo + (size_t)B * H;                 // V*H ushorts
  ushort* wlo   = whi + (size_t)V * H;                 // V*H ushorts
  size_t need = (size_t)((char*)(wlo + (size_t)V * H) - (char*)d_ws);
  const bool use_mfma = ws_size >= need;

  init_k<<<512, 256, 0, stream>>>(emb, h, x);
  if (use_mfma) wsplit_k<<<V * H / 1024, 256, 0, stream>>>(w_dist, whi, wlo);

  const uint32_t base0 = 0u, base1 = 42u;   // jax.random.key(42)
  for (int t = 0; t < S; ++t) {
    uint32_t f0 = 0u, f1 = (uint32_t)t;
    tf2x32(base0, base1, f0, f1);                            // k_t = fold_in(base, t)
    uint32_t k1a = 0u, k1b = 0u; tf2x32(f0, f1, k1a, k1b);   // k1 = enc(0,0)
    uint32_t k2a = 0u, k2b = 1u; tf2x32(f0, f1, k2a, k2b);   // k2 = enc(0,1)

    gemm_gru_k<<<192, 256, 0, stream>>>(x, h, w_ih, w_hh, b_ih, b_hh, gx, gh);
    gru_gates_k<<<512, 256, 0, stream>>>(gx, gh, h, hhi, hlo);
    if (use_mfma)
      gemm_dist_mfma<<<250, 512, 0, stream>>>(hhi, hlo, whi, wlo, b_dist, logits);
    else
      gemm_dist_k<<<500, 256, 0, stream>>>(h, w_dist, b_dist, logits);
    sample_partial_k<<<1024, 256, 0, stream>>>(logits, pm, ps, pbest, pidx,
                                               k1a, k1b, k2a, k2b);
    sample_final_k<<<1, 128, 0, stream>>>(logits, pm, ps, pbest, pidx,
                                          rowm, rowz, samp, out, t, k1a, k1b);
    gather_x_k<<<128, 128, 0, stream>>>(emb, samp, x);
    probs_k<<<125, 256, 0, stream>>>(logits, rowm, rowz, out, t);
  }
}

// Round 5
// 7118.716 us; speedup vs baseline: 2.1847x; 1.2903x over previous
//
#include <hip/hip_runtime.h>
#include <cstdint>
#include <cmath>

#define V 32000
#define E 512
#define H 1024
#define B 128
#define S 64
#define NCHUNK 8
#define CHUNK 4000       // V / NCHUNK
#define BS (B*S)
#define PS 40            // LDS row stride in ushorts (80 B: 16B-aligned, conflict-free)

typedef __attribute__((ext_vector_type(8))) short short8;
typedef __attribute__((ext_vector_type(4))) float f32x4;

// ---------------- threefry2x32 (JAX-exact, 20 rounds) ----------------
#define TFR(x0, x1, r) { x0 += x1; x1 = ((x1) << (r)) | ((x1) >> (32 - (r))); x1 ^= x0; }

__host__ __device__ inline void tf2x32(uint32_t k0, uint32_t k1, uint32_t &x0, uint32_t &x1) {
  uint32_t ks2 = k0 ^ k1 ^ 0x1BD11BDAu;
  x0 += k0; x1 += k1;
  TFR(x0,x1,13) TFR(x0,x1,15) TFR(x0,x1,26) TFR(x0,x1,6)
  x0 += k1;  x1 += ks2 + 1u;
  TFR(x0,x1,17) TFR(x0,x1,29) TFR(x0,x1,16) TFR(x0,x1,24)
  x0 += ks2; x1 += k0 + 2u;
  TFR(x0,x1,13) TFR(x0,x1,15) TFR(x0,x1,26) TFR(x0,x1,6)
  x0 += k0;  x1 += k1 + 3u;
  TFR(x0,x1,17) TFR(x0,x1,29) TFR(x0,x1,16) TFR(x0,x1,24)
  x0 += k1;  x1 += ks2 + 4u;
  TFR(x0,x1,13) TFR(x0,x1,15) TFR(x0,x1,26) TFR(x0,x1,6)
  x0 += ks2; x1 += k0 + 5u;
}

// partitionable threefry 32-bit bits: xor of both output words of enc(hi=0, lo=i)
__device__ __forceinline__ uint32_t tf_bits32(uint32_t ka, uint32_t kb, uint32_t idx) {
  uint32_t x0 = 0u, x1 = idx;
  tf2x32(ka, kb, x0, x1);
  return x0 ^ x1;
}

__device__ __forceinline__ float bits_to_unif(uint32_t b) {
  return __uint_as_float((b >> 9) | 0x3f800000u) - 1.0f;
}

__device__ __forceinline__ float sigmoidf_(float x) { return 1.0f / (1.0f + expf(-x)); }

// bf16 round-to-nearest-even helpers
__device__ __forceinline__ ushort f2bf(float f) {
  uint32_t u = __float_as_uint(f);
  uint32_t r = u + 0x7FFFu + ((u >> 16) & 1u);
  return (ushort)(r >> 16);
}
__device__ __forceinline__ float bf2f(ushort h) { return __uint_as_float(((uint32_t)h) << 16); }

// ---------------- f32 GEMM tile (fallback paths only) ----------------
template<int BM, int BN, int BK, int TM, int TN>
__device__ void gemm_tile(const float* __restrict__ A, const float* __restrict__ Wt,
                          const float* __restrict__ bias, float* __restrict__ C,
                          int N, int K, int mblk, int nblk)
{
  constexpr int WP = BN + 4;
  __shared__ __align__(16) float As[BK][BM];
  __shared__ __align__(16) float Ws[BK][WP];
  const int tid = threadIdx.x;
  constexpr int TX = BN / TN;
  constexpr int TY = BM / TM;
  static_assert(TX * TY == 256, "bad tiling");
  const int tx = tid % TX, ty = tid / TX;
  const int n0 = tx * TN, m0 = ty * TM;

  float acc[TM][TN];
#pragma unroll
  for (int i = 0; i < TM; ++i)
#pragma unroll
    for (int j = 0; j < TN; ++j) acc[i][j] = 0.0f;

  constexpr int NA = (BM * BK / 4) / 256;
  constexpr int NW = (BN * BK / 4) / 256;
  static_assert(NA >= 1 && NW >= 1, "tile too small");

  for (int k0 = 0; k0 < K; k0 += BK) {
    __syncthreads();
#pragma unroll
    for (int q = 0; q < NA; ++q) {
      int idx = q * 256 + tid;
      int m = idx / (BK / 4), c = idx % (BK / 4);
      float4 v = *(const float4*)&A[(size_t)(mblk + m) * K + k0 + 4 * c];
      As[4*c+0][m] = v.x; As[4*c+1][m] = v.y; As[4*c+2][m] = v.z; As[4*c+3][m] = v.w;
    }
#pragma unroll
    for (int q = 0; q < NW; ++q) {
      int idx = q * 256 + tid;
      int n = idx / (BK / 4), c = idx % (BK / 4);
      float4 v = *(const float4*)&Wt[(size_t)(nblk + n) * K + k0 + 4 * c];
      Ws[4*c+0][n] = v.x; Ws[4*c+1][n] = v.y; Ws[4*c+2][n] = v.z; Ws[4*c+3][n] = v.w;
    }
    __syncthreads();
#pragma unroll
    for (int k = 0; k < BK; ++k) {
      float a[TM], w[TN];
#pragma unroll
      for (int i = 0; i < TM; ++i) a[i] = As[k][m0 + i];
#pragma unroll
      for (int j = 0; j < TN; ++j) w[j] = Ws[k][n0 + j];
#pragma unroll
      for (int i = 0; i < TM; ++i)
#pragma unroll
        for (int j = 0; j < TN; ++j) acc[i][j] += a[i] * w[j];
    }
  }
#pragma unroll
  for (int i = 0; i < TM; ++i)
#pragma unroll
    for (int j = 0; j < TN; ++j)
      C[(size_t)(mblk + m0 + i) * N + nblk + n0 + j] = acc[i][j] + bias[nblk + n0 + j];
}

// fallback dist GEMM (f32)
__global__ __launch_bounds__(256) void gemm_dist_k(const float* __restrict__ h,
    const float* __restrict__ w_dist, const float* __restrict__ b_dist,
    float* __restrict__ logits)
{
  gemm_tile<128, 64, 16, 8, 4>(h, w_dist, b_dist, logits, V, H, 0, blockIdx.x * 64);
}

// fallback GRU gemms (f32)
__global__ __launch_bounds__(256) void gemm_gru_k(const float* __restrict__ x,
    const float* __restrict__ h, const float* __restrict__ w_ih, const float* __restrict__ w_hh,
    const float* __restrict__ b_ih, const float* __restrict__ b_hh,
    float* __restrict__ gx, float* __restrict__ gh)
{
  int b = blockIdx.x;
  if (b < 96) {
    int rb = b & 1, cb = b >> 1;
    gemm_tile<64, 64, 16, 4, 4>(x, w_ih, b_ih, gx, 3 * H, E, rb * 64, cb * 64);
  } else {
    b -= 96;
    int rb = b & 1, cb = b >> 1;
    gemm_tile<64, 64, 16, 4, 4>(h, w_hh, b_hh, gh, 3 * H, H, rb * 64, cb * 64);
  }
}

// split f32 -> bf16 hi/lo (once per call); n4 = count of float4 groups
__global__ __launch_bounds__(256) void wsplit_k(const float* __restrict__ w,
    ushort* __restrict__ whi, ushort* __restrict__ wlo, int n4)
{
  int idx = blockIdx.x * 256 + threadIdx.x;
  if (idx >= n4) return;
  size_t i = (size_t)idx * 4;
  float4 v = *(const float4*)&w[i];
  ushort h0 = f2bf(v.x), h1 = f2bf(v.y), h2 = f2bf(v.z), h3 = f2bf(v.w);
  ushort l0 = f2bf(v.x - bf2f(h0)), l1 = f2bf(v.y - bf2f(h1));
  ushort l2 = f2bf(v.z - bf2f(h2)), l3 = f2bf(v.w - bf2f(h3));
  ushort4 hv = {h0, h1, h2, h3}, lv = {l0, l1, l2, l3};
  *(ushort4*)&whi[i] = hv;
  *(ushort4*)&wlo[i] = lv;
}

// GRU gates, h updated in place; also emits bf16 hi/lo split of h
__global__ __launch_bounds__(256) void gru_gates_k(const float* __restrict__ gx,
    const float* __restrict__ gh, float* __restrict__ h,
    ushort* __restrict__ hhi, ushort* __restrict__ hlo)
{
  int idx = blockIdx.x * 256 + threadIdx.x;   // B*H = 131072
  int b = idx >> 10, j = idx & 1023;
  const float* gxb = gx + (size_t)b * 3 * H;
  const float* ghb = gh + (size_t)b * 3 * H;
  float r = sigmoidf_(gxb[j] + ghb[j]);
  float z = sigmoidf_(gxb[H + j] + ghb[H + j]);
  float n = tanhf(gxb[2 * H + j] + r * ghb[2 * H + j]);
  float hn = (1.0f - z) * n + z * h[idx];
  h[idx] = hn;
  ushort hi = f2bf(hn);
  hhi[idx] = hi;
  hlo[idx] = f2bf(hn - bf2f(hi));
}

// ---------------- MFMA bf16x3 dist GEMM ----------------
__global__ __launch_bounds__(512) void gemm_dist_mfma(const ushort* __restrict__ hhi,
    const ushort* __restrict__ hlo, const ushort* __restrict__ whi,
    const ushort* __restrict__ wlo, const float* __restrict__ b_dist,
    float* __restrict__ logits)
{
  __shared__ ushort Ah[128 * PS], Al[128 * PS], Wh[128 * PS], Wl[128 * PS];
  const int tid = threadIdx.x;
  const int wave = tid >> 6, lane = tid & 63;
  const int wm = (wave & 3) * 32;
  const int wn = (wave >> 2) * 64;
  const int nblk = blockIdx.x * 128;
  const int l15 = lane & 15;
  const int q8 = (lane >> 4) * 8;

  f32x4 acc[2][4] = {};
  const int sr = tid >> 2, sc = (tid & 3) * 8;

  for (int k0 = 0; k0 < 1024; k0 += 32) {
    __syncthreads();
    uint4 va = *(const uint4*)&hhi[(size_t)sr * 1024 + k0 + sc];
    uint4 vb = *(const uint4*)&hlo[(size_t)sr * 1024 + k0 + sc];
    uint4 vc = *(const uint4*)&whi[(size_t)(nblk + sr) * 1024 + k0 + sc];
    uint4 vd = *(const uint4*)&wlo[(size_t)(nblk + sr) * 1024 + k0 + sc];
    *(uint4*)&Ah[sr * PS + sc] = va;
    *(uint4*)&Al[sr * PS + sc] = vb;
    *(uint4*)&Wh[sr * PS + sc] = vc;
    *(uint4*)&Wl[sr * PS + sc] = vd;
    __syncthreads();

    short8 ah[2], al[2], wh[4], wl[4];
#pragma unroll
    for (int mt = 0; mt < 2; ++mt) {
      int row = wm + mt * 16 + l15;
      ah[mt] = *(const short8*)&Ah[row * PS + q8];
      al[mt] = *(const short8*)&Al[row * PS + q8];
    }
#pragma unroll
    for (int nt = 0; nt < 4; ++nt) {
      int row = wn + nt * 16 + l15;
      wh[nt] = *(const short8*)&Wh[row * PS + q8];
      wl[nt] = *(const short8*)&Wl[row * PS + q8];
    }
#pragma unroll
    for (int mt = 0; mt < 2; ++mt)
#pragma unroll
      for (int nt = 0; nt < 4; ++nt) {
        acc[mt][nt] = __builtin_amdgcn_mfma_f32_16x16x32_bf16(ah[mt], wh[nt], acc[mt][nt], 0, 0, 0);
        acc[mt][nt] = __builtin_amdgcn_mfma_f32_16x16x32_bf16(al[mt], wh[nt], acc[mt][nt], 0, 0, 0);
        acc[mt][nt] = __builtin_amdgcn_mfma_f32_16x16x32_bf16(ah[mt], wl[nt], acc[mt][nt], 0, 0, 0);
      }
  }

#pragma unroll
  for (int nt = 0; nt < 4; ++nt) {
    int col = nblk + wn + nt * 16 + l15;
    float bv = b_dist[col];
#pragma unroll
    for (int mt = 0; mt < 2; ++mt) {
      int rbase = wm + mt * 16 + (lane >> 4) * 4;
#pragma unroll
      for (int reg = 0; reg < 4; ++reg)
        logits[(size_t)(rbase + reg) * V + col] = acc[mt][nt][reg] + bv;
    }
  }
}

// ---------------- MFMA bf16x3 64x64-tile GEMM (GRU) ----------------
// 256 threads = 4 waves, wave tile 32x32 (2x2 of 16x16), BK=32
__device__ void gemm64_bf16x3(const ushort* __restrict__ Ahi_g, const ushort* __restrict__ Alo_g,
    const ushort* __restrict__ Whi_g, const ushort* __restrict__ Wlo_g,
    const float* __restrict__ bias, float* __restrict__ C,
    int N, int K, int mblk, int nblk)
{
  __shared__ ushort Ah[64 * PS], Al[64 * PS], Wh[64 * PS], Wl[64 * PS];
  const int tid = threadIdx.x;
  const int wave = tid >> 6, lane = tid & 63;
  const int wm = (wave & 1) * 32, wn = (wave >> 1) * 32;
  const int l15 = lane & 15, q8 = (lane >> 4) * 8;
  const int sr = tid >> 2, sc = (tid & 3) * 8;

  f32x4 acc[2][2] = {};

  for (int k0 = 0; k0 < K; k0 += 32) {
    __syncthreads();
    uint4 va = *(const uint4*)&Ahi_g[(size_t)(mblk + sr) * K + k0 + sc];
    uint4 vb = *(const uint4*)&Alo_g[(size_t)(mblk + sr) * K + k0 + sc];
    uint4 vc = *(const uint4*)&Whi_g[(size_t)(nblk + sr) * K + k0 + sc];
    uint4 vd = *(const uint4*)&Wlo_g[(size_t)(nblk + sr) * K + k0 + sc];
    *(uint4*)&Ah[sr * PS + sc] = va;
    *(uint4*)&Al[sr * PS + sc] = vb;
    *(uint4*)&Wh[sr * PS + sc] = vc;
    *(uint4*)&Wl[sr * PS + sc] = vd;
    __syncthreads();

    short8 ah[2], al[2], wh[2], wl[2];
#pragma unroll
    for (int mt = 0; mt < 2; ++mt) {
      int row = wm + mt * 16 + l15;
      ah[mt] = *(const short8*)&Ah[row * PS + q8];
      al[mt] = *(const short8*)&Al[row * PS + q8];
    }
#pragma unroll
    for (int nt = 0; nt < 2; ++nt) {
      int row = wn + nt * 16 + l15;
      wh[nt] = *(const short8*)&Wh[row * PS + q8];
      wl[nt] = *(const short8*)&Wl[row * PS + q8];
    }
#pragma unroll
    for (int mt = 0; mt < 2; ++mt)
#pragma unroll
      for (int nt = 0; nt < 2; ++nt) {
        acc[mt][nt] = __builtin_amdgcn_mfma_f32_16x16x32_bf16(ah[mt], wh[nt], acc[mt][nt], 0, 0, 0);
        acc[mt][nt] = __builtin_amdgcn_mfma_f32_16x16x32_bf16(al[mt], wh[nt], acc[mt][nt], 0, 0, 0);
        acc[mt][nt] = __builtin_amdgcn_mfma_f32_16x16x32_bf16(ah[mt], wl[nt], acc[mt][nt], 0, 0, 0);
      }
  }

#pragma unroll
  for (int nt = 0; nt < 2; ++nt) {
    int col = nblk + wn + nt * 16 + l15;
    float bv = bias[col];
#pragma unroll
    for (int mt = 0; mt < 2; ++mt) {
      int rbase = mblk + wm + mt * 16 + (lane >> 4) * 4;
#pragma unroll
      for (int reg = 0; reg < 4; ++reg)
        C[(size_t)(rbase + reg) * N + col] = acc[mt][nt][reg] + bv;
    }
  }
}

// one dispatch for gx (blocks 0..95) + gh (blocks 96..191).
// gx is 128x3072 -> 2 row-tiles x 48 col-tiles = 96 blocks (R4 bug: used 48).
__global__ __launch_bounds__(256) void gemm_gru_mfma(
    const ushort* __restrict__ xhi, const ushort* __restrict__ xlo,
    const ushort* __restrict__ hhi, const ushort* __restrict__ hlo,
    const ushort* __restrict__ wihhi, const ushort* __restrict__ wihlo,
    const ushort* __restrict__ whhhi, const ushort* __restrict__ whhlo,
    const float* __restrict__ b_ih, const float* __restrict__ b_hh,
    float* __restrict__ gx, float* __restrict__ gh)
{
  int b = blockIdx.x;
  if (b < 96) {
    int mblk = (b & 1) * 64, nblk = (b >> 1) * 64;
    gemm64_bf16x3(xhi, xlo, wihhi, wihlo, b_ih, gx, 3 * H, E, mblk, nblk);
  } else {
    b -= 96;
    int mblk = (b & 1) * 64, nblk = (b >> 1) * 64;
    gemm64_bf16x3(hhi, hlo, whhhi, whhlo, b_hh, gh, 3 * H, H, mblk, nblk);
  }
}

// init: h = 0 (and its bf16 splits), x = broadcast emb[0] (and its bf16 splits)
__global__ __launch_bounds__(256) void init_k(const float* __restrict__ emb,
    float* __restrict__ h, float* __restrict__ x,
    ushort* __restrict__ hhi, ushort* __restrict__ hlo,
    ushort* __restrict__ xhi, ushort* __restrict__ xlo)
{
  int i = blockIdx.x * 256 + threadIdx.x;   // grid covers B*H
  if (i < B * H) { h[i] = 0.0f; hhi[i] = 0; hlo[i] = 0; }
  if (i < B * E) {
    float v = emb[i & (E - 1)];
    x[i] = v;
    ushort hi = f2bf(v);
    xhi[i] = hi;
    xlo[i] = f2bf(v - bf2f(hi));
  }
}

// fused pass: per (row, v-chunk) online softmax partials AND gumbel-argmax partials
__global__ __launch_bounds__(256) void sample_partial_k(const float* __restrict__ logits,
    float* __restrict__ pm, float* __restrict__ ps,
    float* __restrict__ pbest, int* __restrict__ pidx,
    uint32_t k1a, uint32_t k1b, uint32_t k2a, uint32_t k2b)
{
  const int b = blockIdx.x & 127, chunk = blockIdx.x >> 7;
  const int tid = threadIdx.x;
  const bool draw = bits_to_unif(tf_bits32(k1a, k1b, (uint32_t)b)) <= 0.05f;
  const float LOGU = -logf((float)V);
  const int vbeg = chunk * CHUNK, vend = vbeg + CHUNK;
  float m0 = -INFINITY, s0 = 0.0f, best = -INFINITY;
  int bi = 2147483647;
  for (int v = vbeg + tid; v < vend; v += 256) {
    float a = logits[(size_t)b * V + v];
    if (a > m0) { s0 = s0 * expf(m0 - a) + 1.0f; m0 = a; } else { s0 += expf(a - m0); }
    uint32_t bits = tf_bits32(k2a, k2b, (uint32_t)(b * V + v));
    float g = -logf(-logf(bits_to_unif(bits)));
    float key = draw ? (LOGU + g) : (a + g);
    if (key > best) { best = key; bi = v; }
  }
  __shared__ float shm[256], shs[256], sv[256];
  __shared__ int si[256];
  shm[tid] = m0; shs[tid] = s0; sv[tid] = best; si[tid] = bi;
  __syncthreads();
  for (int off = 128; off > 0; off >>= 1) {
    if (tid < off) {
      float ma = shm[tid], sa = shs[tid];
      float mb = shm[tid + off], sb = shs[tid + off];
      float M = fmaxf(ma, mb);
      shm[tid] = M;
      shs[tid] = sa * expf(ma - M) + sb * expf(mb - M);
      float va = sv[tid], vb = sv[tid + off];
      int ia = si[tid], ib = si[tid + off];
      if (vb > va || (vb == va && ib < ia)) { sv[tid] = vb; si[tid] = ib; }
    }
    __syncthreads();
  }
  if (tid == 0) {
    pm[b * NCHUNK + chunk] = shm[0]; ps[b * NCHUNK + chunk] = shs[0];
    pbest[b * NCHUNK + chunk] = sv[0]; pidx[b * NCHUNK + chunk] = si[0];
  }
}

// fused final: block b = row b. Thread 0 combines chunk partials, emits outputs;
// then the whole block gathers x = emb[sampled] (f32 + bf16 split).
__global__ __launch_bounds__(128) void sample_final_gather_k(const float* __restrict__ logits,
    const float* __restrict__ pm, const float* __restrict__ ps,
    const float* __restrict__ pbest, const int* __restrict__ pidx,
    float* __restrict__ rowm, float* __restrict__ rowz, int* __restrict__ samp,
    const float* __restrict__ emb, float* __restrict__ x,
    ushort* __restrict__ xhi, ushort* __restrict__ xlo,
    float* __restrict__ out, int t, uint32_t k1a, uint32_t k1b)
{
  __shared__ int sh_idx;
  const int b = blockIdx.x, tid = threadIdx.x;
  if (tid == 0) {
    float m0 = -INFINITY, s0 = 0.0f;
#pragma unroll
    for (int c = 0; c < NCHUNK; ++c) {
      float ma = pm[b * NCHUNK + c], sa = ps[b * NCHUNK + c];
      float M = fmaxf(m0, ma); s0 = s0 * expf(m0 - M) + sa * expf(ma - M); m0 = M;
    }
    float z0 = logf(s0);
    rowm[b] = m0; rowz[b] = z0;
    float best = pbest[b * NCHUNK]; int idx = pidx[b * NCHUNK];
#pragma unroll
    for (int c = 1; c < NCHUNK; ++c) {
      float v = pbest[b * NCHUNK + c];
      if (v > best) { best = v; idx = pidx[b * NCHUNK + c]; }
    }
    float lp = (logits[(size_t)b * V + idx] - m0) - z0;
    bool draw = bits_to_unif(tf_bits32(k1a, k1b, (uint32_t)b)) <= 0.05f;
    float corr = 1.0f;
    if (draw) {
      const float LOGU = -logf((float)V);
      float onp = fminf(fmaxf(expf(lp), 1e-8f), 1.0f);
      float offp = fminf(fmaxf(expf(LOGU), 1e-8f), 1.0f);
      corr = onp / offp;
    }
    out[b * S + t] = (float)idx;
    out[BS + b * S + t] = corr;
    out[2 * BS + b * S + t] = lp;
    samp[b] = idx;
    sh_idx = idx;
  }
  __syncthreads();
  const int row = sh_idx;
  float4 v = *(const float4*)&emb[(size_t)row * E + tid * 4];
  *(float4*)&x[(size_t)b * E + tid * 4] = v;
  ushort h0 = f2bf(v.x), h1 = f2bf(v.y), h2 = f2bf(v.z), h3 = f2bf(v.w);
  ushort l0 = f2bf(v.x - bf2f(h0)), l1 = f2bf(v.y - bf2f(h1));
  ushort l2 = f2bf(v.z - bf2f(h2)), l3 = f2bf(v.w - bf2f(h3));
  ushort4 hv = {h0, h1, h2, h3}, lv = {l0, l1, l2, l3};
  *(ushort4*)&xhi[(size_t)b * E + tid * 4] = hv;
  *(ushort4*)&xlo[(size_t)b * E + tid * 4] = lv;
}

// probs[t, v] = mean_b exp(dist[b, v])
__global__ __launch_bounds__(256) void probs_k(const float* __restrict__ logits,
    const float* __restrict__ rowm, const float* __restrict__ rowz,
    float* __restrict__ out, int t)
{
  __shared__ float sm[B], sz[B];
  const int tid = threadIdx.x;
  if (tid < B) { sm[tid] = rowm[tid]; sz[tid] = rowz[tid]; }
  __syncthreads();
  int v = blockIdx.x * 256 + tid;
  float acc = 0.0f;
  for (int b = 0; b < B; ++b) acc += expf((logits[(size_t)b * V + v] - sm[b]) - sz[b]);
  out[3 * BS + (size_t)t * V + v] = acc * (1.0f / 128.0f);
}

extern "C" void kernel_launch(void* const* d_in, const int* in_sizes, int n_in,
                              void* d_out, int out_size, void* d_ws, size_t ws_size,
                              hipStream_t stream) {
  (void)in_sizes; (void)n_in; (void)out_size;
  const float* emb    = (const float*)d_in[0];
  const float* w_ih   = (const float*)d_in[1];
  const float* w_hh   = (const float*)d_in[2];
  const float* b_ih   = (const float*)d_in[3];
  const float* b_hh   = (const float*)d_in[4];
  const float* w_dist = (const float*)d_in[5];
  const float* b_dist = (const float*)d_in[6];
  float* out = (float*)d_out;

  float* ws = (float*)d_ws;
  float* h      = ws;                      // B*H
  float* x      = h + B * H;               // B*E
  float* gx     = x + B * E;               // B*3H
  float* gh     = gx + B * 3 * H;          // B*3H
  float* logits = gh + B * 3 * H;          // B*V
  float* pm     = logits + (size_t)B * V;  // B*NCHUNK
  float* ps     = pm + B * NCHUNK;
  float* pbest  = ps + B * NCHUNK;
  int*   pidx   = (int*)(pbest + B * NCHUNK);
  float* rowm   = (float*)(pidx + B * NCHUNK);
  float* rowz   = rowm + B;
  int*   samp   = (int*)(rowz + B);
  ushort* hhi   = (ushort*)(samp + B);                 // B*H
  ushort* hlo   = hhi + (size_t)B * H;                 // B*H
  // dist split region
  ushort* whi   = hlo + (size_t)B * H;                 // V*H
  ushort* wlo   = whi + (size_t)V * H;                 // V*H
  // gru split region
  ushort* xhi   = wlo + (size_t)V * H;                 // B*E
  ushort* xlo   = xhi + (size_t)B * E;                 // B*E
  ushort* wihhi = xlo + (size_t)B * E;                 // 3H*E
  ushort* wihlo = wihhi + (size_t)3 * H * E;           // 3H*E
  ushort* whhhi = wihlo + (size_t)3 * H * E;           // 3H*H
  ushort* whhlo = whhhi + (size_t)3 * H * H;           // 3H*H

  size_t need_dist = (size_t)((char*)xhi - (char*)d_ws);
  size_t need_gru  = (size_t)((char*)(whhlo + (size_t)3 * H * H) - (char*)d_ws);
  const bool use_dist_mfma = ws_size >= need_dist;
  const bool use_gru_mfma  = ws_size >= need_gru;

  init_k<<<512, 256, 0, stream>>>(emb, h, x, hhi, hlo, xhi, xlo);
  if (use_dist_mfma)
    wsplit_k<<<(V * H / 4 + 255) / 256, 256, 0, stream>>>(w_dist, whi, wlo, V * H / 4);
  if (use_gru_mfma) {
    wsplit_k<<<(3 * H * E / 4 + 255) / 256, 256, 0, stream>>>(w_ih, wihhi, wihlo, 3 * H * E / 4);
    wsplit_k<<<(3 * H * H / 4 + 255) / 256, 256, 0, stream>>>(w_hh, whhhi, whhlo, 3 * H * H / 4);
  }

  const uint32_t base0 = 0u, base1 = 42u;   // jax.random.key(42)
  for (int t = 0; t < S; ++t) {
    uint32_t f0 = 0u, f1 = (uint32_t)t;
    tf2x32(base0, base1, f0, f1);                            // k_t = fold_in(base, t)
    uint32_t k1a = 0u, k1b = 0u; tf2x32(f0, f1, k1a, k1b);   // k1 = enc(0,0)
    uint32_t k2a = 0u, k2b = 1u; tf2x32(f0, f1, k2a, k2b);   // k2 = enc(0,1)

    if (use_gru_mfma)
      gemm_gru_mfma<<<192, 256, 0, stream>>>(xhi, xlo, hhi, hlo, wihhi, wihlo,
                                             whhhi, whhlo, b_ih, b_hh, gx, gh);
    else
      gemm_gru_k<<<192, 256, 0, stream>>>(x, h, w_ih, w_hh, b_ih, b_hh, gx, gh);
    gru_gates_k<<<512, 256, 0, stream>>>(gx, gh, h, hhi, hlo);
    if (use_dist_mfma)
      gemm_dist_mfma<<<250, 512, 0, stream>>>(hhi, hlo, whi, wlo, b_dist, logits);
    else
      gemm_dist_k<<<500, 256, 0, stream>>>(h, w_dist, b_dist, logits);
    sample_partial_k<<<1024, 256, 0, stream>>>(logits, pm, ps, pbest, pidx,
                                               k1a, k1b, k2a, k2b);
    sample_final_gather_k<<<128, 128, 0, stream>>>(logits, pm, ps, pbest, pidx,
                                                   rowm, rowz, samp, emb, x, xhi, xlo,
                                                   out, t, k1a, k1b);
    probs_k<<<125, 256, 0, stream>>>(logits, rowm, rowz, out, t);
  }
}